// Round 5
// baseline (667.070 us; speedup 1.0000x reference)
//
#include <hip/hip_runtime.h>
#include <hip/hip_cooperative_groups.h>

namespace cg = cooperative_groups;

#define LVAL 256
#define T    32
#define ST   36          // slab row stride (floats): 144 B, 16B-aligned
#define SLAB (T * ST)    // 1152 floats per slab
#define NB   8
#define NEG  (-1e30f)

// waits LDS write retirement + stops compiler reordering memory ops
#define LDS_FENCE() asm volatile("s_waitcnt lgkmcnt(0)" ::: "memory")

__device__ __forceinline__ size_t sidx(int b, int i, int e) {
    return ((size_t)b << 16) + (i << 8) + e;
}

// Phase 1: t[b,i,e] = max_c scores[b,i,e,c] -> f32 s[b][i][e], strict upper only.
__global__ __launch_bounds__(256) void phase1(const float* __restrict__ scores,
                                              float* __restrict__ s) {
    const int i = blockIdx.x, b = blockIdx.y;
    const int sub = threadIdx.x & 15, slot = threadIdx.x >> 4;
    const float* row = scores + ((((size_t)b * LVAL + i) * LVAL) << 6);
    #pragma unroll 4
    for (int m0 = 0; m0 < LVAL; m0 += 16) {
        const int e = m0 + slot;
        if (e > i) {
            float4 v = *((const float4*)(row + ((size_t)e << 6)) + sub);
            float mx = fmaxf(fmaxf(v.x, v.y), fmaxf(v.z, v.w));
            #pragma unroll
            for (int d = 1; d < 16; d <<= 1) mx = fmaxf(mx, __shfl_xor(mx, d));
            if (sub == 0) s[sidx(b, i, e)] = mx;
        }
    }
}

// Fused DP: round0 + rounds D=1..7 + finalize, one cooperative kernel, 64 WGs.
__global__ __launch_bounds__(256)
void dp_coop(float* __restrict__ s, const int* __restrict__ lens,
             float* __restrict__ out) {
    __shared__ float smem[14 * SLAB];               // 64512 B static LDS
    float (*Ae)[ST]   = (float(*)[ST])(smem + 0 * SLAB);
    float (*BeT)[ST]  = (float(*)[ST])(smem + 1 * SLAB);
    float (*cur)[ST]  = (float(*)[ST])(smem + 2 * SLAB);
    float (*curT)[ST] = (float(*)[ST])(smem + 3 * SLAB);
    float (*tb)[ST]   = (float(*)[ST])(smem + 4 * SLAB);
    float (*pre)[ST]  = (float(*)[ST])(smem + 5 * SLAB);
    // per-wave GEMM slabs: AT[w] (A transposed / partial results), BW[w] (B row-major)
    float* ATb = smem + 6 * SLAB;                   // 4 slabs
    float* BWb = smem + 10 * SLAB;                  // 4 slabs

    cg::grid_group grid = cg::this_grid();
    const int tid  = threadIdx.x;
    const int wid  = tid >> 6, lane = tid & 63;
    const int lr   = tid >> 5, lc   = tid & 31;
    const int grow = lane >> 1, gc16 = (lane & 1) * 16;   // GEMM load mapping
    const int gly  = lane >> 3, glx  = lane & 7;          // GEMM 8x8 lane grid
    const int r0   = 4 * gly,  c0   = 4 * glx;

    // ---------------- round 0: diagonal blocks ----------------
    {
        const int b = blockIdx.x >> 3, bi = blockIdx.x & 7;
        #pragma unroll
        for (int r = 0; r < 4; ++r) {
            const int row = lr + 8 * r;
            tb[row][lc]   = s[sidx(b, bi * T + row, bi * T + lc)];
            cur[row][lc]  = NEG;
            curT[row][lc] = NEG;
        }
        __syncthreads();
        if (tid < T - 1) {                      // w==1 diagonal = t (final)
            float v = tb[tid][tid + 1];
            cur[tid][tid + 1] = v;
            curT[tid + 1][tid] = v;
        }
        __syncthreads();
        if (wid == 0) {
            for (int l = 2; l < T; ++l) {
                const int cells = T - l;
                const int logP = (cells > 16) ? 1 : (cells > 8) ? 2 : (cells > 4) ? 3
                               : (cells > 2) ? 4 : (cells > 1) ? 5 : 6;
                const int P = 1 << logP;
                const int c = lane >> logP, p = lane & (P - 1);
                const int li = c, le = c + l;
                float acc = NEG;
                for (int sv = p; sv < 8; sv += P) {
                    float4 u  = *(const float4*)&cur[li][4 * sv];
                    float4 w4 = *(const float4*)&curT[le][4 * sv];
                    acc = fmaxf(acc, fmaxf(fmaxf(u.x + w4.x, u.y + w4.y),
                                           fmaxf(u.z + w4.z, u.w + w4.w)));
                }
                for (int d2 = 1; d2 < P; d2 <<= 1) acc = fmaxf(acc, __shfl_xor(acc, d2));
                if (c < cells) {
                    float v = acc + tb[li][le];
                    if (p == 0) cur[li][le] = v;
                    if (p == 1) curT[le][li] = v;
                }
                LDS_FENCE();
            }
        }
        __syncthreads();
        #pragma unroll
        for (int r = 0; r < 4; ++r) {
            const int row = lr + 8 * r;
            if (lc > row) s[sidx(b, bi * T + row, bi * T + lc)] = cur[row][lc];
        }
    }
    grid.sync();

    // ---------------- rounds D = 1..7 ----------------
    for (int D = 1; D < NB; ++D) {
        const int nbi = NB - D;
        if (blockIdx.x < nbi * 8) {
            const int b = blockIdx.x / nbi, bi = blockIdx.x % nbi, be = bi + D;
            const int nw = (D - 1 < 4) ? (D - 1) : 4;
            float (*AT)[ST] = (float(*)[ST])(ATb + wid * SLAB);
            float (*BW)[ST] = (float(*)[ST])(BWb + wid * SLAB);

            // GEMM over middle K blocks, split across waves, 4x4 register tiles
            float ag[4][4];
            #pragma unroll
            for (int i = 0; i < 4; ++i)
                #pragma unroll
                for (int j = 0; j < 4; ++j) ag[i][j] = NEG;
            for (int K = bi + 1 + wid; K < be; K += 4) {
                #pragma unroll
                for (int j4 = 0; j4 < 4; ++j4) {
                    float4 av = *(const float4*)&s[sidx(b, bi * T + grow, K * T + gc16 + 4 * j4)];
                    AT[gc16 + 4 * j4 + 0][grow] = av.x;
                    AT[gc16 + 4 * j4 + 1][grow] = av.y;
                    AT[gc16 + 4 * j4 + 2][grow] = av.z;
                    AT[gc16 + 4 * j4 + 3][grow] = av.w;
                    float4 bv = *(const float4*)&s[sidx(b, K * T + grow, be * T + gc16 + 4 * j4)];
                    *(float4*)&BW[grow][gc16 + 4 * j4] = bv;
                }
                LDS_FENCE();
                #pragma unroll 4
                for (int k = 0; k < T; ++k) {
                    float4 a4 = *(const float4*)&AT[k][r0];
                    float4 b4 = *(const float4*)&BW[k][c0];
                    const float aa[4] = {a4.x, a4.y, a4.z, a4.w};
                    const float bb[4] = {b4.x, b4.y, b4.z, b4.w};
                    #pragma unroll
                    for (int i = 0; i < 4; ++i)
                        #pragma unroll
                        for (int j = 0; j < 4; ++j)
                            ag[i][j] = fmaxf(ag[i][j], aa[i] + bb[j]);
                }
                LDS_FENCE();
            }
            if (wid < nw) {                        // store wave partial into AT slab
                #pragma unroll
                for (int i = 0; i < 4; ++i)
                    *(float4*)&AT[r0 + i][c0] =
                        make_float4(ag[i][0], ag[i][1], ag[i][2], ag[i][3]);
            }
            // edge operands (all threads): left diag, right diag^T, target t, cur=NEG
            #pragma unroll
            for (int r = 0; r < 4; ++r) {
                const int row = lr + 8 * r;
                float va = s[sidx(b, bi * T + row, bi * T + lc)];
                Ae[row][lc] = (lc > row) ? va : NEG;
                float vb = s[sidx(b, be * T + row, be * T + lc)];
                BeT[lc][row] = (row < lc) ? vb : NEG;
                tb[row][lc] = s[sidx(b, bi * T + row, be * T + lc)];
                cur[row][lc] = NEG;
                curT[row][lc] = NEG;
            }
            __syncthreads();
            #pragma unroll
            for (int r = 0; r < 4; ++r) {          // combine wave partials -> pre
                const int row = lr + 8 * r;
                float v = NEG;
                for (int w2 = 0; w2 < nw; ++w2)
                    v = fmaxf(v, *(ATb + w2 * SLAB + row * ST + lc));
                pre[row][lc] = v;
            }
            __syncthreads();

            if (wid == 0) {                        // barrier-free 63-step edge pass
                for (int l = 0; l < 2 * T - 1; ++l) {
                    const int delta = l - (T - 1);
                    const int ad = delta < 0 ? -delta : delta;
                    const int cells = T - ad;
                    const int logP = (cells > 16) ? 1 : (cells > 8) ? 2 : (cells > 4) ? 3
                                   : (cells > 2) ? 4 : (cells > 1) ? 5 : 6;
                    const int P = 1 << logP;
                    const int c = lane >> logP, p = lane & (P - 1);
                    const int li = c + (delta < 0 ? ad : 0);
                    const int le = li + delta;
                    float acc = NEG;
                    for (int sv = p; sv < 16; sv += P) {
                        float4 u, w4;
                        if (sv < 8) {              // split in left edge block
                            u  = *(const float4*)&Ae[li][4 * sv];
                            w4 = *(const float4*)&curT[le][4 * sv];
                        } else {                   // split in right edge block
                            u  = *(const float4*)&cur[li][4 * (sv - 8)];
                            w4 = *(const float4*)&BeT[le][4 * (sv - 8)];
                        }
                        acc = fmaxf(acc, fmaxf(fmaxf(u.x + w4.x, u.y + w4.y),
                                               fmaxf(u.z + w4.z, u.w + w4.w)));
                    }
                    if (p == 0) acc = fmaxf(acc, pre[li][le]);
                    for (int d2 = 1; d2 < P; d2 <<= 1) acc = fmaxf(acc, __shfl_xor(acc, d2));
                    if (c < cells) {
                        float v;
                        if (D == 1 && delta == -(T - 1)) v = tb[li][le];   // w == 1
                        else v = acc + tb[li][le];
                        if (p == 0) cur[li][le] = v;
                        if (p == 1) curT[le][li] = v;
                    }
                    LDS_FENCE();
                }
            }
            __syncthreads();
            #pragma unroll
            for (int r = 0; r < 4; ++r) {
                const int row = lr + 8 * r;
                s[sidx(b, bi * T + row, be * T + lc)] = cur[row][lc];
            }
        }
        grid.sync();
    }

    if (blockIdx.x == 0 && tid < 8) {
        int len = lens[tid];
        len = len < 1 ? 1 : (len > LVAL - 1 ? LVAL - 1 : len);
        out[tid] = s[sidx(tid, 0, len)];
    }
}

extern "C" void kernel_launch(void* const* d_in, const int* in_sizes, int n_in,
                              void* d_out, int out_size, void* d_ws, size_t ws_size,
                              hipStream_t stream) {
    const float* scores = (const float*)d_in[0];
    const int*   lens   = (const int*)d_in[1];
    float*       out    = (float*)d_out;
    float*       s      = (float*)d_ws;            // 8 * 256 * 256 f32 = 2 MB

    phase1<<<dim3(LVAL, 8), 256, 0, stream>>>(scores, s);

    void* args[] = {(void*)&s, (void*)&lens, (void*)&out};
    hipLaunchCooperativeKernel((void*)dp_coop, dim3(64), dim3(256), args, 0, stream);
}

// Round 6
// 354.058 us; speedup vs baseline: 1.8841x; 1.8841x over previous
//
#include <hip/hip_runtime.h>

#define LVAL 256
#define T    32
#define ST   36          // slab row stride (floats): 144 B, 16B-aligned
#define SLAB (T * ST)
#define NB   8
#define NEG  (-1e30f)

// wave-synchronous LDS step fence: drain DS ops + block compiler reordering
#define LDS_FENCE() asm volatile("s_waitcnt lgkmcnt(0)" ::: "memory")

__device__ __forceinline__ size_t sidx(int b, int i, int e) {
    return ((size_t)b << 16) + (i << 8) + e;
}

// VALU cross-lane max via DPP quad_perm (no LDS/swizzle latency)
template<int CTRL>
__device__ __forceinline__ float dpp_max(float v) {
#if __has_builtin(__builtin_amdgcn_mov_dpp)
    int o = __builtin_amdgcn_mov_dpp(__builtin_bit_cast(int, v), CTRL, 0xF, 0xF, true);
    return fmaxf(v, __builtin_bit_cast(float, o));
#else
    return fmaxf(v, __shfl_xor(v, CTRL == 0xB1 ? 1 : 2));
#endif
}

// Phase 1: t[b,i,e] = max_c scores[b,i,e,c] -> f32 s[b][i][e], strict upper only.
__global__ __launch_bounds__(256) void phase1(const float* __restrict__ scores,
                                              float* __restrict__ s) {
    const int i = blockIdx.x, b = blockIdx.y;
    const int sub = threadIdx.x & 15, slot = threadIdx.x >> 4;
    const float* row = scores + ((((size_t)b * LVAL + i) * LVAL) << 6);
    #pragma unroll 4
    for (int m0 = 0; m0 < LVAL; m0 += 16) {
        const int e = m0 + slot;
        if (e > i) {
            float4 v = *((const float4*)(row + ((size_t)e << 6)) + sub);
            float mx = fmaxf(fmaxf(v.x, v.y), fmaxf(v.z, v.w));
            #pragma unroll
            for (int d = 1; d < 16; d <<= 1) mx = fmaxf(mx, __shfl_xor(mx, d));
            if (sub == 0) s[sidx(b, i, e)] = mx;
        }
    }
}

// One wave-synchronous DP step inside a diagonal block (round 0).
template<int LP>
__device__ __forceinline__ void diag_step(int lane, int l,
                                          float (*cur)[ST], float (*curT)[ST],
                                          const float (*tb)[ST]) {
    const int cells = T - l;
    const int P = 1 << LP;
    const int c = lane >> LP, p = lane & (P - 1);
    const bool guard = c < cells;
    const int li = guard ? c : 0;
    const int le = guard ? c + l : 0;
    constexpr int NF = 8 >> LP;
    const float tv = tb[li][le];
    float acc = NEG;
    #pragma unroll
    for (int m = 0; m < NF; ++m) {
        const int k0 = 4 * (p + m * P);
        float4 cu = *(const float4*)&cur[li][k0];
        float4 ct = *(const float4*)&curT[le][k0];
        acc = fmaxf(acc, fmaxf(fmaxf(cu.x + ct.x, cu.y + ct.y),
                               fmaxf(cu.z + ct.z, cu.w + ct.w)));
    }
    acc = dpp_max<0xB1>(acc);                 // xor 1
    if (LP >= 2) acc = dpp_max<0x4E>(acc);    // xor 2
    const float v = acc + tv;
    if (guard && p == 0) cur[li][le] = v;
    if (guard && p == 1) curT[le][li] = v;
}

// Round 0: diagonal blocks, one wave per block, fully wave-synchronous.
__global__ __launch_bounds__(64) void round0(float* __restrict__ s) {
    __shared__ __align__(16) float curS[SLAB], curTS[SLAB], tbS[SLAB];
    float (*cur)[ST]  = (float(*)[ST])curS;
    float (*curT)[ST] = (float(*)[ST])curTS;
    float (*tb)[ST]   = (float(*)[ST])tbS;
    const int bi = blockIdx.x & 7, b = blockIdx.x >> 3;
    const int lane = threadIdx.x;
    const int row = lane >> 1, ch = (lane & 1) * 16;
    const float4 negv = make_float4(NEG, NEG, NEG, NEG);
    #pragma unroll
    for (int j = 0; j < 4; ++j) {
        float4 v = *(const float4*)&s[sidx(b, bi * T + row, bi * T + ch + 4 * j)];
        *(float4*)&tb[row][ch + 4 * j]   = v;
        *(float4*)&cur[row][ch + 4 * j]  = negv;
        *(float4*)&curT[row][ch + 4 * j] = negv;
    }
    LDS_FENCE();
    if (lane < T - 1) {                        // w == 1 diagonal = t (final)
        float v = tb[lane][lane + 1];
        cur[lane][lane + 1] = v;
        curT[lane + 1][lane] = v;
    }
    LDS_FENCE();
    #pragma unroll 1
    for (int l = 2; l < T; ++l) {
        if (T - l <= 16) diag_step<2>(lane, l, cur, curT, tb);
        else             diag_step<1>(lane, l, cur, curT, tb);
        LDS_FENCE();
    }
    #pragma unroll
    for (int j = 0; j < 4; ++j)
        *(float4*)&s[sidx(b, bi * T + row, bi * T + ch + 4 * j)] =
            *(const float4*)&cur[row][ch + 4 * j];
}

// One wave-synchronous edge step of round D. All splits scanned maskless:
// Ae/BeT pre-masked with NEG, cur/curT hold NEG in not-yet-final slots.
template<int LP>
__device__ __forceinline__ void edge_step(int lane, int l, int D,
                                          const float (*Ae)[ST], const float (*BeT)[ST],
                                          float (*cur)[ST], float (*curT)[ST],
                                          const float (*tb)[ST], const float (*pre)[ST]) {
    const int delta = l - (T - 1);
    const int ad = delta < 0 ? -delta : delta;
    const int cells = T - ad;
    const int P = 1 << LP;
    const int c = lane >> LP, p = lane & (P - 1);
    const bool guard = c < cells;
    const int li = guard ? (delta < 0 ? c + ad : c) : 0;
    const int le = guard ? li + delta : 0;
    constexpr int NF = 8 >> LP;
    const float tv = tb[li][le];
    float acc = pre[li][le];                   // middle-K GEMM partial (NEG if none)
    #pragma unroll
    for (int m = 0; m < NF; ++m) {
        const int k0 = 4 * (p + m * P);
        float4 a  = *(const float4*)&Ae[li][k0];     // split in left edge block
        float4 ct = *(const float4*)&curT[le][k0];
        float4 cu = *(const float4*)&cur[li][k0];    // split in right edge block
        float4 bt = *(const float4*)&BeT[le][k0];
        float s0 = fmaxf(fmaxf(a.x + ct.x, a.y + ct.y), fmaxf(a.z + ct.z, a.w + ct.w));
        float s1 = fmaxf(fmaxf(cu.x + bt.x, cu.y + bt.y), fmaxf(cu.z + bt.z, cu.w + bt.w));
        acc = fmaxf(acc, fmaxf(s0, s1));
    }
    acc = dpp_max<0xB1>(acc);
    if (LP >= 2) acc = dpp_max<0x4E>(acc);
    const float v = (D == 1 && l == 0) ? tv : acc + tv;   // w==1 cell: value is t
    if (guard && p == 0) cur[li][le] = v;
    if (guard && p == 1) curT[le][li] = v;
}

// Round D: GEMM over middle K blocks (4-wave split, static unroll) + single-wave
// 63-step edge pass + store. D==7 also writes the final outputs.
__global__ __launch_bounds__(256) void roundD(float* __restrict__ s, int D,
                                              const int* __restrict__ lens,
                                              float* __restrict__ out) {
    __shared__ __align__(16) float smem[14 * SLAB];      // 64512 B
    float (*Ae)[ST]   = (float(*)[ST])(smem + 0 * SLAB);
    float (*BeT)[ST]  = (float(*)[ST])(smem + 1 * SLAB);
    float (*cur)[ST]  = (float(*)[ST])(smem + 2 * SLAB);
    float (*curT)[ST] = (float(*)[ST])(smem + 3 * SLAB);
    float (*tb)[ST]   = (float(*)[ST])(smem + 4 * SLAB);
    float (*pre)[ST]  = (float(*)[ST])(smem + 5 * SLAB);
    float* ATb = smem + 6 * SLAB;                        // 4 per-wave A^T slabs
    float* BWb = smem + 10 * SLAB;                       // 4 per-wave B slabs

    const int nbi = NB - D;
    const int b = blockIdx.x / nbi, bi = blockIdx.x % nbi, be = bi + D;
    const int tid = threadIdx.x, wid = tid >> 6, lane = tid & 63;
    const int lr = tid >> 5, lc = tid & 31;
    const int grow = lane >> 1, gc = (lane & 1) * 16;
    const int gly = lane >> 3, glx = lane & 7, r0 = 4 * gly, c0 = 4 * glx;
    const int nw = (D - 1 < 4) ? (D - 1) : 4;
    float (*AT)[ST] = (float(*)[ST])(ATb + wid * SLAB);
    float (*BW)[ST] = (float(*)[ST])(BWb + wid * SLAB);

    // GEMM: wave-private K blocks, statically unrolled inner loops
    float ag[4][4];
    #pragma unroll
    for (int i = 0; i < 4; ++i)
        #pragma unroll
        for (int j = 0; j < 4; ++j) ag[i][j] = NEG;
    for (int K = bi + 1 + wid; K < be; K += 4) {
        #pragma unroll
        for (int j = 0; j < 4; ++j) {
            float4 av = *(const float4*)&s[sidx(b, bi * T + grow, K * T + gc + 4 * j)];
            AT[gc + 4 * j + 0][grow] = av.x;
            AT[gc + 4 * j + 1][grow] = av.y;
            AT[gc + 4 * j + 2][grow] = av.z;
            AT[gc + 4 * j + 3][grow] = av.w;
            float4 bv = *(const float4*)&s[sidx(b, K * T + grow, be * T + gc + 4 * j)];
            *(float4*)&BW[grow][gc + 4 * j] = bv;
        }
        LDS_FENCE();                                   // wave-private slabs
        #pragma unroll 4
        for (int k = 0; k < T; ++k) {
            float4 a4 = *(const float4*)&AT[k][r0];
            float4 b4 = *(const float4*)&BW[k][c0];
            const float aa[4] = {a4.x, a4.y, a4.z, a4.w};
            const float bb[4] = {b4.x, b4.y, b4.z, b4.w};
            #pragma unroll
            for (int i = 0; i < 4; ++i)
                #pragma unroll
                for (int j = 0; j < 4; ++j)
                    ag[i][j] = fmaxf(ag[i][j], aa[i] + bb[j]);
        }
        LDS_FENCE();
    }
    if (wid < nw) {
        #pragma unroll
        for (int i = 0; i < 4; ++i)
            *(float4*)&AT[r0 + i][c0] = make_float4(ag[i][0], ag[i][1], ag[i][2], ag[i][3]);
    }
    // edge operands: masked diag blocks + target t + NEG-filled cur/curT
    #pragma unroll
    for (int r = 0; r < 4; ++r) {
        const int row = lr + 8 * r;
        float va = s[sidx(b, bi * T + row, bi * T + lc)];
        Ae[row][lc] = (lc > row) ? va : NEG;
        float vb = s[sidx(b, be * T + row, be * T + lc)];
        BeT[lc][row] = (row < lc) ? vb : NEG;
        tb[row][lc] = s[sidx(b, bi * T + row, be * T + lc)];
        cur[row][lc] = NEG;
        curT[row][lc] = NEG;
    }
    __syncthreads();
    #pragma unroll
    for (int r = 0; r < 4; ++r) {                     // combine wave partials
        const int row = lr + 8 * r;
        float v = NEG;
        for (int w2 = 0; w2 < nw; ++w2)
            v = fmaxf(v, ATb[w2 * SLAB + row * ST + lc]);
        pre[row][lc] = v;
    }
    __syncthreads();

    if (wid == 0) {                                   // barrier-free edge pass
        #pragma unroll 1
        for (int l = 0; l < 2 * T - 1; ++l) {
            const int ad0 = (l < T - 1) ? (T - 1 - l) : (l - (T - 1));
            if (ad0 >= 16) edge_step<2>(lane, l, D, Ae, BeT, cur, curT, tb, pre);
            else           edge_step<1>(lane, l, D, Ae, BeT, cur, curT, tb, pre);
            LDS_FENCE();
        }
    }
    __syncthreads();
    #pragma unroll
    for (int r = 0; r < 4; ++r)
        s[sidx(b, bi * T + lr + 8 * r, be * T + lc)] = cur[lr + 8 * r][lc];

    if (D == NB - 1 && tid == 0) {                    // fused finalize (bi==0 blocks)
        int len = lens[b];
        len = len < 1 ? 1 : (len > LVAL - 1 ? LVAL - 1 : len);
        out[b] = (len >= (NB - 1) * T) ? cur[0][len - (NB - 1) * T]
                                       : s[sidx(b, 0, len)];
    }
}

extern "C" void kernel_launch(void* const* d_in, const int* in_sizes, int n_in,
                              void* d_out, int out_size, void* d_ws, size_t ws_size,
                              hipStream_t stream) {
    const float* scores = (const float*)d_in[0];
    const int*   lens   = (const int*)d_in[1];
    float*       out    = (float*)d_out;
    float*       s      = (float*)d_ws;               // 8 * 256 * 256 f32 = 2 MB

    phase1<<<dim3(LVAL, 8), 256, 0, stream>>>(scores, s);
    round0<<<64, 64, 0, stream>>>(s);
    for (int D = 1; D < NB; ++D)
        roundD<<<(NB - D) * 8, 256, 0, stream>>>(s, D, lens, out);
}